// Round 5
// baseline (185.095 us; speedup 1.0000x reference)
//
#include <hip/hip_runtime.h>

#define GAMMA 0.1f
#define MIN_R 0.1f

// Counting-sort-by-range parameters
#define NRP 128                 // nodes per range (power of 2)
#define LOG_NR 7
#define S3 (3 * NRP)            // floats per range slice (384)
#define NB 256                  // blocks for count/scatter kernels
#define THR 256                 // threads for count/scatter/process
#define RMAX 1024               // max ranges (n_nodes <= 131072, matches 17-bit src)

// ---------------- phase A: per-block range histogram -------------------------
__global__ __launch_bounds__(THR) void count_kernel(
    const int* __restrict__ dst, unsigned* __restrict__ counts,
    int n_edges, int epb, int R)
{
    __shared__ unsigned hist[RMAX];
    const int b = blockIdx.x, t = threadIdx.x;
    for (int i = t; i < R; i += THR) hist[i] = 0u;
    __syncthreads();
    const int s0 = b * epb;
    const int s1 = min(s0 + epb, n_edges);
    for (int base = s0 + t * 4; base < s1; base += THR * 4) {
        if (base + 3 < s1) {
            int4 d4 = *(const int4*)(dst + base);
            atomicAdd(&hist[(unsigned)d4.x >> LOG_NR], 1u);
            atomicAdd(&hist[(unsigned)d4.y >> LOG_NR], 1u);
            atomicAdd(&hist[(unsigned)d4.z >> LOG_NR], 1u);
            atomicAdd(&hist[(unsigned)d4.w >> LOG_NR], 1u);
        } else {
            for (int e = base; e < s1; ++e)
                atomicAdd(&hist[(unsigned)dst[e] >> LOG_NR], 1u);
        }
    }
    __syncthreads();
    for (int i = t; i < R; i += THR) counts[(size_t)b * R + i] = hist[i];
}

// ---------------- phase B1: per-bin exclusive scan over blocks ---------------
// grid = R blocks, NB threads. bases[b][r] = sum_{b'<b} counts[b'][r]; totals[r].
__global__ __launch_bounds__(NB) void scan_blocks_kernel(
    const unsigned* __restrict__ counts, unsigned* __restrict__ bases,
    unsigned* __restrict__ totals, int R)
{
    __shared__ unsigned s[NB];
    const int r = blockIdx.x, t = threadIdx.x;
    unsigned orig = counts[(size_t)t * R + r];
    s[t] = orig;
    __syncthreads();
    for (int d = 1; d < NB; d <<= 1) {
        unsigned v = (t >= d) ? s[t - d] : 0u;
        __syncthreads();
        s[t] += v;
        __syncthreads();
    }
    bases[(size_t)t * R + r] = s[t] - orig;   // exclusive
    if (t == NB - 1) totals[r] = s[t];
}

// ---------------- phase B2: exclusive scan over bins (1024-wide) -------------
__global__ __launch_bounds__(1024) void scan_bins_kernel(
    const unsigned* __restrict__ totals, unsigned* __restrict__ offsets, int R)
{
    __shared__ unsigned s[1024];
    const int t = threadIdx.x;
    unsigned v = (t < R) ? totals[t] : 0u;
    s[t] = v;
    __syncthreads();
    for (int d = 1; d < 1024; d <<= 1) {
        unsigned u = (t >= d) ? s[t - d] : 0u;
        __syncthreads();
        s[t] += u;
        __syncthreads();
    }
    if (t < R) offsets[t] = s[t] - v;         // exclusive
    if (t == R - 1) offsets[R] = s[t];
}

// ---------------- phase C: scatter packed edges into bins --------------------
__global__ __launch_bounds__(THR) void scatter_kernel(
    const int* __restrict__ src, const int* __restrict__ dst,
    const unsigned* __restrict__ bases, const unsigned* __restrict__ offsets,
    unsigned* __restrict__ pk, int n_edges, int epb, int R)
{
    __shared__ unsigned cursor[RMAX];
    const int b = blockIdx.x, t = threadIdx.x;
    for (int i = t; i < R; i += THR)
        cursor[i] = bases[(size_t)b * R + i] + offsets[i];
    __syncthreads();
    const int s0 = b * epb;
    const int s1 = min(s0 + epb, n_edges);
    for (int base = s0 + t * 4; base < s1; base += THR * 4) {
        if (base + 3 < s1) {
            int4 d4 = *(const int4*)(dst + base);
            int4 s4 = *(const int4*)(src + base);
            #pragma unroll
            for (int k = 0; k < 4; ++k) {
                unsigned d = (unsigned)((k == 0) ? d4.x : (k == 1) ? d4.y : (k == 2) ? d4.z : d4.w);
                unsigned s = (unsigned)((k == 0) ? s4.x : (k == 1) ? s4.y : (k == 2) ? s4.z : s4.w);
                unsigned pos = atomicAdd(&cursor[d >> LOG_NR], 1u);
                pk[pos] = ((d & (NRP - 1)) << 17) | s;
            }
        } else {
            for (int e = base; e < s1; ++e) {
                unsigned d = (unsigned)dst[e];
                unsigned pos = atomicAdd(&cursor[d >> LOG_NR], 1u);
                pk[pos] = ((d & (NRP - 1)) << 17) | (unsigned)src[e];
            }
        }
    }
}

// ---------------- phase D: dense per-range LJ accumulate + direct write ------
// grid = R blocks. Block r owns nodes [r*NRP, (r+1)*NRP): accumulate its bin's
// edges in 1.5 KB LDS, then write out = acc - GAMMA*v directly. No slabs.
__device__ __forceinline__ void lj_one(unsigned p, const float* __restrict__ x,
                                       const float* __restrict__ xr,
                                       float* __restrict__ acc) {
    int s = (int)(p & 0x1FFFFu);
    int u = (int)(p >> 17);
    float3 xs = *(const float3*)(x + 3 * s);   // dwordx3, one transaction
    float dx = xr[3 * u + 0] - xs.x;
    float dy = xr[3 * u + 1] - xs.y;
    float dz = xr[3 * u + 2] - xs.z;
    float r2 = dx * dx + dy * dy + dz * dz;
    float rr = sqrtf(r2);
    float inv_norm = 1.0f / fmaxf(rr, 1e-12f);
    float rc = fmaxf(rr, MIN_R);
    float s1 = 1.0f / rc;                      // RC = 1
    float s2 = s1 * s1;
    float s6 = s2 * s2 * s2;
    float F = 4.0f * s6 * (12.0f * s6 - 6.0f) * s1;
    float sc = F * inv_norm;
    atomicAdd(&acc[3 * u + 0], sc * dx);
    atomicAdd(&acc[3 * u + 1], sc * dy);
    atomicAdd(&acc[3 * u + 2], sc * dz);
}

__global__ __launch_bounds__(THR) void process_kernel(
    const float* __restrict__ x, const float* __restrict__ v,
    const unsigned* __restrict__ pk, const unsigned* __restrict__ offsets,
    float* __restrict__ out, int n_nodes)
{
    __shared__ __align__(16) float acc[S3];
    __shared__ __align__(16) float xr[S3];
    const int r = blockIdx.x, t = threadIdx.x;
    const int xbase = 3 * r * NRP;
    const int xlim = 3 * n_nodes;
    for (int i = t; i < S3; i += THR) {
        acc[i] = 0.0f;
        int g = xbase + i;
        xr[i] = (g < xlim) ? x[g] : 0.0f;
    }
    __syncthreads();

    const int e0 = (int)offsets[r];
    const int e1 = (int)offsets[r + 1];
    // 2-edge ILP
    for (int e = e0 + t * 2; e < e1; e += THR * 2) {
        unsigned p0 = pk[e];
        bool h = (e + 1 < e1);
        unsigned p1 = h ? pk[e + 1] : 0u;
        lj_one(p0, x, xr, acc);
        if (h) lj_one(p1, x, xr, acc);
    }
    __syncthreads();

    for (int i = t; i < S3; i += THR) {
        int g = xbase + i;
        if (g < xlim) out[g] = acc[i] - GAMMA * v[g];
    }
}

// ---------------- fallback path ----------------------------------------------
__global__ void init_out_kernel(const float* __restrict__ v,
                                float* __restrict__ out, int n) {
    int i = blockIdx.x * blockDim.x + threadIdx.x;
    if (i < n) out[i] = -GAMMA * v[i];
}

__global__ void edge_atomic_kernel(const float* __restrict__ x,
                                   const int* __restrict__ src,
                                   const int* __restrict__ dst,
                                   float* __restrict__ out, int n_edges) {
    int e = blockIdx.x * blockDim.x + threadIdx.x;
    if (e < n_edges) {
        int s = src[e], d = dst[e];
        float dx = x[3 * d + 0] - x[3 * s + 0];
        float dy = x[3 * d + 1] - x[3 * s + 1];
        float dz = x[3 * d + 2] - x[3 * s + 2];
        float rr = sqrtf(dx * dx + dy * dy + dz * dz);
        float inv_norm = 1.0f / fmaxf(rr, 1e-12f);
        float rc = fmaxf(rr, MIN_R);
        float s1 = 1.0f / rc;
        float s2 = s1 * s1;
        float s6 = s2 * s2 * s2;
        float F = 4.0f * s6 * (12.0f * s6 - 6.0f) * s1;
        float sc = F * inv_norm;
        unsafeAtomicAdd(&out[3 * d + 0], sc * dx);
        unsafeAtomicAdd(&out[3 * d + 1], sc * dy);
        unsafeAtomicAdd(&out[3 * d + 2], sc * dz);
    }
}

extern "C" void kernel_launch(void* const* d_in, const int* in_sizes, int n_in,
                              void* d_out, int out_size, void* d_ws, size_t ws_size,
                              hipStream_t stream) {
    const float* x   = (const float*)d_in[0];
    const float* v   = (const float*)d_in[1];
    const int*   src = (const int*)d_in[2];
    const int*   dst = (const int*)d_in[3];
    float* out = (float*)d_out;

    const int n_out = out_size;
    const int n_nodes = out_size / 3;
    const int n_edges = in_sizes[2];
    const int R = (n_nodes + NRP - 1) / NRP;

    // ws layout (u32 units for tables)
    const size_t counts_off  = 0;                        // NB*R
    const size_t bases_off   = (size_t)NB * R;           // NB*R
    const size_t totals_off  = 2 * (size_t)NB * R;       // R
    const size_t offsets_off = totals_off + R;           // R+1
    const size_t tables_end  = offsets_off + R + 1;
    const size_t pk_byte_off = ((tables_end * 4) + 63) & ~(size_t)63;
    const size_t need = pk_byte_off + (size_t)n_edges * 4;

    if (n_nodes <= (1 << 17) && R <= RMAX && need <= ws_size) {
        unsigned* tables  = (unsigned*)d_ws;
        unsigned* counts  = tables + counts_off;
        unsigned* bases   = tables + bases_off;
        unsigned* totals  = tables + totals_off;
        unsigned* offsets = tables + offsets_off;
        unsigned* pk      = (unsigned*)((char*)d_ws + pk_byte_off);

        int epb = ((n_edges + NB - 1) / NB + 3) & ~3;

        count_kernel<<<NB, THR, 0, stream>>>(dst, counts, n_edges, epb, R);
        scan_blocks_kernel<<<R, NB, 0, stream>>>(counts, bases, totals, R);
        scan_bins_kernel<<<1, 1024, 0, stream>>>(totals, offsets, R);
        scatter_kernel<<<NB, THR, 0, stream>>>(src, dst, bases, offsets, pk,
                                               n_edges, epb, R);
        process_kernel<<<R, THR, 0, stream>>>(x, v, pk, offsets, out, n_nodes);
    } else {
        int blk = 256;
        init_out_kernel<<<(n_out + blk - 1) / blk, blk, 0, stream>>>(v, out, n_out);
        edge_atomic_kernel<<<(n_edges + blk - 1) / blk, blk, 0, stream>>>(
            x, src, dst, out, n_edges);
    }
}